// Round 2
// baseline (684.614 us; speedup 1.0000x reference)
//
#include <hip/hip_runtime.h>
#include <hip/hip_bf16.h>

typedef unsigned short u16;

#define NDIM 128
#define EDIM 32

__device__ __forceinline__ float bf2f(u16 u) {
    union { unsigned int i; float f; } v; v.i = ((unsigned int)u) << 16; return v.f;
}
__device__ __forceinline__ u16 f2bf(float f) {
    __hip_bfloat16 h = __float2bfloat16(f);
    return *reinterpret_cast<u16*>(&h);
}

// dtype-adaptive load helpers. BF=true: data is bf16; BF=false: data is fp32.
template<bool BF>
__device__ __forceinline__ float ld1(const void* p, long i) {
    if (BF) return bf2f(((const u16*)p)[i]);
    return ((const float*)p)[i];
}
template<bool BF>
__device__ __forceinline__ float4 ld4(const void* p, long i) {
    if (BF) {
        ushort4 v = *(const ushort4*)((const u16*)p + i);
        return make_float4(bf2f(v.x), bf2f(v.y), bf2f(v.z), bf2f(v.w));
    }
    return *(const float4*)((const float*)p + i);
}

// ---------------------------------------------------------------------------
// K0: dtype detector. If x is fp32, the LOW u16 of each fp32 has a
// uniform-random "bf16 exponent" field; if x is bf16 N(0,1), exponents
// cluster in [100,150]. flag: 1 = bf16, 0 = fp32.
// ---------------------------------------------------------------------------
__global__ void detect_kernel(const void* __restrict__ x, int* __restrict__ flag) {
    __shared__ int cnt;
    if (threadIdx.x == 0) cnt = 0;
    __syncthreads();
    const u16* p = (const u16*)x;
    int crazy = 0;
    for (int i = threadIdx.x; i < 512; i += 64) {
        u16 v = p[2 * i];
        int e = (v >> 7) & 0xFF;
        if (e != 0 && (e < 100 || e > 150)) crazy++;
    }
    atomicAdd(&cnt, crazy);
    __syncthreads();
    if (threadIdx.x == 0) *flag = (cnt > 128) ? 0 : 1;
}

// ---------------------------------------------------------------------------
// K1: edge embed (relu(edge_attr @ We + be)) + message scatter-add into agg
// ---------------------------------------------------------------------------
template<bool BF>
__global__ __launch_bounds__(256) void edge_kernel(
    const void* __restrict__ edge_attr, const int* __restrict__ ei,
    const void* __restrict__ x, const void* __restrict__ We,
    const void* __restrict__ be, float* __restrict__ agg, int E,
    const int* __restrict__ flag) {
    if ((*flag != 0) != BF) return;
    __shared__ float WeLds[EDIM * NDIM];
    __shared__ float beLds[NDIM];
    for (int i = threadIdx.x; i < EDIM * NDIM; i += 256) WeLds[i] = ld1<BF>(We, i);
    if (threadIdx.x < NDIM) beLds[threadIdx.x] = ld1<BF>(be, threadIdx.x);
    __syncthreads();

    const int lane = threadIdx.x & 63;
    const int wave = blockIdx.x * 4 + (threadIdx.x >> 6);
    const int nwaves = gridDim.x * 4;

    for (int e = wave; e < E; e += nwaves) {
        int src = ei[e];
        int dst = ei[E + e];
        float av = (lane < EDIM) ? ld1<BF>(edge_attr, (long)e * EDIM + lane) : 0.0f;
        float acc0 = 0.0f, acc1 = 0.0f;
#pragma unroll
        for (int k = 0; k < EDIM; ++k) {
            float ak = __shfl(av, k);
            acc0 += ak * WeLds[k * NDIM + lane];
            acc1 += ak * WeLds[k * NDIM + 64 + lane];
        }
        float ef0 = fmaxf(acc0 + beLds[lane], 0.0f);
        float ef1 = fmaxf(acc1 + beLds[64 + lane], 0.0f);
        float m0 = ld1<BF>(x, (long)src * NDIM + lane) + ef0;
        float m1 = ld1<BF>(x, (long)src * NDIM + 64 + lane) + ef1;
        atomicAdd(&agg[dst * NDIM + lane], m0);
        atomicAdd(&agg[dst * NDIM + 64 + lane], m1);
    }
}

// ---------------------------------------------------------------------------
// K2: h0 = (1+eps)*x + agg ; h1 = h0 @ W1 + b1 ; accumulate col sum/sumsq
// block: 64 rows x 128 cols; thread: 8 rows x 4 cols
// ---------------------------------------------------------------------------
template<bool BF>
__global__ __launch_bounds__(256) void gemm1_kernel(
    const void* __restrict__ x, const float* __restrict__ agg,
    const void* __restrict__ eps_p, const void* __restrict__ W,
    const void* __restrict__ b, float* __restrict__ hout,
    float* __restrict__ stats, int M, const int* __restrict__ flag) {
    if ((*flag != 0) != BF) return;
    __shared__ float hT[64 * 129];
    __shared__ float redS[8][NDIM];
    __shared__ float redQ[8][NDIM];

    const int tid = threadIdx.x;
    const int row0 = blockIdx.x * 64;
    const float onepeps = 1.0f + ld1<BF>(eps_p, 0);

#pragma unroll
    for (int i = 0; i < 8; ++i) {
        int idx = (tid + i * 256) * 4;
        int r = idx >> 7, c = idx & 127;
        int row = row0 + r;
        float v0 = 0.f, v1 = 0.f, v2 = 0.f, v3 = 0.f;
        if (row < M) {
            const float4 ag = *(const float4*)(agg + (long)row * NDIM + c);
            const float4 xv = ld4<BF>(x, (long)row * NDIM + c);
            v0 = onepeps * xv.x + ag.x;
            v1 = onepeps * xv.y + ag.y;
            v2 = onepeps * xv.z + ag.z;
            v3 = onepeps * xv.w + ag.w;
        }
        hT[r * 129 + c + 0] = v0;
        hT[r * 129 + c + 1] = v1;
        hT[r * 129 + c + 2] = v2;
        hT[r * 129 + c + 3] = v3;
    }
    __syncthreads();

    const int tx = tid & 31, ty = tid >> 5;
    const int c0 = tx * 4;
    float acc[8][4];
#pragma unroll
    for (int j = 0; j < 4; ++j) {
        float bj = ld1<BF>(b, c0 + j);
#pragma unroll
        for (int r = 0; r < 8; ++r) acc[r][j] = bj;
    }

    for (int k = 0; k < NDIM; ++k) {
        float4 wv = ld4<BF>(W, (long)k * NDIM + c0);
#pragma unroll
        for (int r = 0; r < 8; ++r) {
            float a = hT[(ty * 8 + r) * 129 + k];
            acc[r][0] += a * wv.x;
            acc[r][1] += a * wv.y;
            acc[r][2] += a * wv.z;
            acc[r][3] += a * wv.w;
        }
    }

    float s0 = 0.f, s1 = 0.f, s2 = 0.f, s3 = 0.f;
    float q0 = 0.f, q1 = 0.f, q2 = 0.f, q3 = 0.f;
#pragma unroll
    for (int r = 0; r < 8; ++r) {
        int row = row0 + ty * 8 + r;
        if (row < M) {
            *(float4*)(hout + (long)row * NDIM + c0) =
                make_float4(acc[r][0], acc[r][1], acc[r][2], acc[r][3]);
            s0 += acc[r][0]; q0 += acc[r][0] * acc[r][0];
            s1 += acc[r][1]; q1 += acc[r][1] * acc[r][1];
            s2 += acc[r][2]; q2 += acc[r][2] * acc[r][2];
            s3 += acc[r][3]; q3 += acc[r][3] * acc[r][3];
        }
    }
    redS[ty][c0] = s0; redS[ty][c0 + 1] = s1; redS[ty][c0 + 2] = s2; redS[ty][c0 + 3] = s3;
    redQ[ty][c0] = q0; redQ[ty][c0 + 1] = q1; redQ[ty][c0 + 2] = q2; redQ[ty][c0 + 3] = q3;
    __syncthreads();
    if (tid < NDIM) {
        float t = 0.f;
#pragma unroll
        for (int w = 0; w < 8; ++w) t += redS[w][tid];
        atomicAdd(&stats[tid], t);
    } else {
        int c = tid - NDIM;
        float t = 0.f;
#pragma unroll
        for (int w = 0; w < 8; ++w) t += redQ[w][c];
        atomicAdd(&stats[NDIM + c], t);
    }
}

// ---------------------------------------------------------------------------
// K3: a = relu(BN1(h1)) ; h2 = a @ W2 + b2 ; accumulate col sum/sumsq
// ---------------------------------------------------------------------------
template<bool BF>
__global__ __launch_bounds__(256) void gemm2_kernel(
    const float* __restrict__ h1, const float* __restrict__ statsIn,
    const void* __restrict__ g, const void* __restrict__ beta,
    const void* __restrict__ W, const void* __restrict__ b,
    float* __restrict__ hout, float* __restrict__ stats, int M,
    const int* __restrict__ flag) {
    if ((*flag != 0) != BF) return;
    __shared__ float hT[64 * 129];
    __shared__ float redS[8][NDIM];
    __shared__ float redQ[8][NDIM];
    __shared__ float scaleL[NDIM];
    __shared__ float shiftL[NDIM];

    const int tid = threadIdx.x;
    const int row0 = blockIdx.x * 64;

    if (tid < NDIM) {
        float s = statsIn[tid], q = statsIn[NDIM + tid];
        float invM = 1.0f / (float)M;
        float mean = s * invM;
        float var = fmaxf(q * invM - mean * mean, 0.0f) + 1e-5f;
        float sc = ld1<BF>(g, tid) * rsqrtf(var);
        scaleL[tid] = sc;
        shiftL[tid] = ld1<BF>(beta, tid) - mean * sc;
    }
    __syncthreads();

#pragma unroll
    for (int i = 0; i < 8; ++i) {
        int idx = (tid + i * 256) * 4;
        int r = idx >> 7, c = idx & 127;
        int row = row0 + r;
        float v0 = 0.f, v1 = 0.f, v2 = 0.f, v3 = 0.f;
        if (row < M) {
            const float4 hv = *(const float4*)(h1 + (long)row * NDIM + c);
            v0 = fmaxf(hv.x * scaleL[c + 0] + shiftL[c + 0], 0.0f);
            v1 = fmaxf(hv.y * scaleL[c + 1] + shiftL[c + 1], 0.0f);
            v2 = fmaxf(hv.z * scaleL[c + 2] + shiftL[c + 2], 0.0f);
            v3 = fmaxf(hv.w * scaleL[c + 3] + shiftL[c + 3], 0.0f);
        }
        hT[r * 129 + c + 0] = v0;
        hT[r * 129 + c + 1] = v1;
        hT[r * 129 + c + 2] = v2;
        hT[r * 129 + c + 3] = v3;
    }
    __syncthreads();

    const int tx = tid & 31, ty = tid >> 5;
    const int c0 = tx * 4;
    float acc[8][4];
#pragma unroll
    for (int j = 0; j < 4; ++j) {
        float bj = ld1<BF>(b, c0 + j);
#pragma unroll
        for (int r = 0; r < 8; ++r) acc[r][j] = bj;
    }

    for (int k = 0; k < NDIM; ++k) {
        float4 wv = ld4<BF>(W, (long)k * NDIM + c0);
#pragma unroll
        for (int r = 0; r < 8; ++r) {
            float a = hT[(ty * 8 + r) * 129 + k];
            acc[r][0] += a * wv.x;
            acc[r][1] += a * wv.y;
            acc[r][2] += a * wv.z;
            acc[r][3] += a * wv.w;
        }
    }

    float s0 = 0.f, s1 = 0.f, s2 = 0.f, s3 = 0.f;
    float q0 = 0.f, q1 = 0.f, q2 = 0.f, q3 = 0.f;
#pragma unroll
    for (int r = 0; r < 8; ++r) {
        int row = row0 + ty * 8 + r;
        if (row < M) {
            *(float4*)(hout + (long)row * NDIM + c0) =
                make_float4(acc[r][0], acc[r][1], acc[r][2], acc[r][3]);
            s0 += acc[r][0]; q0 += acc[r][0] * acc[r][0];
            s1 += acc[r][1]; q1 += acc[r][1] * acc[r][1];
            s2 += acc[r][2]; q2 += acc[r][2] * acc[r][2];
            s3 += acc[r][3]; q3 += acc[r][3] * acc[r][3];
        }
    }
    redS[ty][c0] = s0; redS[ty][c0 + 1] = s1; redS[ty][c0 + 2] = s2; redS[ty][c0 + 3] = s3;
    redQ[ty][c0] = q0; redQ[ty][c0 + 1] = q1; redQ[ty][c0 + 2] = q2; redQ[ty][c0 + 3] = q3;
    __syncthreads();
    if (tid < NDIM) {
        float t = 0.f;
#pragma unroll
        for (int w = 0; w < 8; ++w) t += redS[w][tid];
        atomicAdd(&stats[tid], t);
    } else {
        int c = tid - NDIM;
        float t = 0.f;
#pragma unroll
        for (int w = 0; w < 8; ++w) t += redQ[w][c];
        atomicAdd(&stats[NDIM + c], t);
    }
}

// ---------------------------------------------------------------------------
// K4: out = relu(BN2(h2)) -> output dtype
// ---------------------------------------------------------------------------
template<bool BF>
__global__ __launch_bounds__(256) void bn2_out_kernel(
    const float* __restrict__ h2, const float* __restrict__ statsIn,
    const void* __restrict__ g, const void* __restrict__ beta,
    void* __restrict__ out, int M, const int* __restrict__ flag) {
    if ((*flag != 0) != BF) return;
    __shared__ float scaleL[NDIM];
    __shared__ float shiftL[NDIM];
    const int tid = threadIdx.x;
    if (tid < NDIM) {
        float s = statsIn[tid], q = statsIn[NDIM + tid];
        float invM = 1.0f / (float)M;
        float mean = s * invM;
        float var = fmaxf(q * invM - mean * mean, 0.0f) + 1e-5f;
        float sc = ld1<BF>(g, tid) * rsqrtf(var);
        scaleL[tid] = sc;
        shiftL[tid] = ld1<BF>(beta, tid) - mean * sc;
    }
    __syncthreads();

    const int n4 = M * NDIM / 4;
    for (int i = blockIdx.x * 256 + tid; i < n4; i += gridDim.x * 256) {
        int c = (i & 31) * 4;
        float4 hv = *(const float4*)(h2 + (long)i * 4);
        float o0 = fmaxf(hv.x * scaleL[c + 0] + shiftL[c + 0], 0.0f);
        float o1 = fmaxf(hv.y * scaleL[c + 1] + shiftL[c + 1], 0.0f);
        float o2 = fmaxf(hv.z * scaleL[c + 2] + shiftL[c + 2], 0.0f);
        float o3 = fmaxf(hv.w * scaleL[c + 3] + shiftL[c + 3], 0.0f);
        if (BF) {
            ushort4 o;
            o.x = f2bf(o0); o.y = f2bf(o1); o.z = f2bf(o2); o.w = f2bf(o3);
            *(ushort4*)((u16*)out + (long)i * 4) = o;
        } else {
            *(float4*)((float*)out + (long)i * 4) = make_float4(o0, o1, o2, o3);
        }
    }
}

extern "C" void kernel_launch(void* const* d_in, const int* in_sizes, int n_in,
                              void* d_out, int out_size, void* d_ws, size_t ws_size,
                              hipStream_t stream) {
    const void* x         = d_in[0];
    const int*  ei        = (const int*)d_in[1];
    const void* edge_attr = d_in[2];
    const void* eps_p     = d_in[3];
    const void* We        = d_in[4];
    const void* be        = d_in[5];
    const void* W1        = d_in[6];
    const void* b1        = d_in[7];
    const void* g1        = d_in[8];
    const void* beta1     = d_in[9];
    const void* W2        = d_in[10];
    const void* b2        = d_in[11];
    const void* g2        = d_in[12];
    const void* beta2     = d_in[13];

    const int N = in_sizes[0] / NDIM;          // 50000
    const int E = in_sizes[1] / 2;             // 800000
    const size_t nd = (size_t)N * NDIM;        // 6.4M

    float* agg    = (float*)d_ws;              // [N*128] fp32; reused as h2
    float* h1     = agg + nd;                  // [N*128] fp32
    float* stats1 = h1 + nd;                   // [256]: sum, sumsq
    float* stats2 = stats1 + 256;              // [256]
    int*   flag   = (int*)(stats2 + 256);
    float* h2     = agg;                       // reuse

    detect_kernel<<<1, 64, 0, stream>>>(x, flag);
    hipMemsetAsync(agg, 0, nd * sizeof(float), stream);
    hipMemsetAsync(stats1, 0, 512 * sizeof(float), stream);

    const int nblk = (N + 63) / 64;

    edge_kernel<false><<<2048, 256, 0, stream>>>(edge_attr, ei, x, We, be, agg, E, flag);
    edge_kernel<true ><<<2048, 256, 0, stream>>>(edge_attr, ei, x, We, be, agg, E, flag);

    gemm1_kernel<false><<<nblk, 256, 0, stream>>>(x, agg, eps_p, W1, b1, h1, stats1, N, flag);
    gemm1_kernel<true ><<<nblk, 256, 0, stream>>>(x, agg, eps_p, W1, b1, h1, stats1, N, flag);

    gemm2_kernel<false><<<nblk, 256, 0, stream>>>(h1, stats1, g1, beta1, W2, b2, h2, stats2, N, flag);
    gemm2_kernel<true ><<<nblk, 256, 0, stream>>>(h1, stats1, g1, beta1, W2, b2, h2, stats2, N, flag);

    bn2_out_kernel<false><<<2048, 256, 0, stream>>>(h2, stats2, g2, beta2, d_out, N, flag);
    bn2_out_kernel<true ><<<2048, 256, 0, stream>>>(h2, stats2, g2, beta2, d_out, N, flag);
}